// Round 6
// baseline (772.160 us; speedup 1.0000x reference)
//
#include <hip/hip_runtime.h>

// ---------- types & helpers ----------
typedef __attribute__((ext_vector_type(8))) short sh8;   // 8 x bf16 (4 VGPRs)
typedef __attribute__((ext_vector_type(4))) float f4;    // MFMA accum / float4

__device__ __forceinline__ float bf2f(unsigned short u) {
    union { unsigned int u; float f; } c; c.u = ((unsigned int)u) << 16; return c.f;
}
__device__ __forceinline__ unsigned short f2bf(float f) {
    union { float f; unsigned int u; } c; c.f = f;
    unsigned int x = c.u;
    unsigned int r = (x + 0x7fffu + ((x >> 16) & 1u)) >> 16;   // RNE
    return (unsigned short)r;
}
__device__ __forceinline__ void bfsplit(float x, short& hi, short& lo) {
    unsigned short h = f2bf(x);
    float r = x - bf2f(h);
    hi = (short)h;
    lo = (short)f2bf(r);
}
// actual XCD id of the executing wave (HW_REG_XCC_ID = hwreg 20).
// simm16 = (size-1)<<11 | offset<<6 | id = (31<<11)|20 = 63508.
// If this ever returns junk, the work-stealing queues still guarantee correctness.
__device__ __forceinline__ int my_xcd() {
    return (int)(__builtin_amdgcn_s_getreg(63508) & 7u);
}

#define FILL_CH 4096   // edges per work-queue chunk

// ---------- CSR build ----------
__global__ void k_zero_cnt(int* cnt, int* queues, int N) {
    int i = blockIdx.x * 256 + threadIdx.x;
    if (i < N) cnt[i] = 0;
    if (blockIdx.x == 0 && threadIdx.x < 16) queues[threadIdx.x] = 0;
}

// XCD-bound count: group g owns dst range [g*N/8,(g+1)*N/8). Blocks drain their own
// XCD's chunk queue first, then steal from others (correctness never depends on mapping).
__global__ void k_count(const int* __restrict__ dst, int* __restrict__ cnt,
                        int* __restrict__ queue, int E, int N, int nChunks) {
    __shared__ int sT;
    int xcd = my_xcd();
    for (int gi = 0; gi < 8; ++gi) {
        int gg = (xcd + gi) & 7;
        int lo = (int)((long long)gg * N / 8);
        int hi = (int)((long long)(gg + 1) * N / 8);
        for (;;) {
            if (threadIdx.x == 0) sT = atomicAdd(&queue[gg], 1);
            __syncthreads();
            int t = sT;
            __syncthreads();
            if (t >= nChunks) break;
            int base = t * FILL_CH;
            int end = base + FILL_CH; if (end > E) end = E;
            for (int e = base + threadIdx.x; e < end; e += 256) {
                int d = dst[e];
                if (d >= lo && d < hi) atomicAdd(&cnt[d], 1);
            }
        }
    }
}

#define SCAN_B 256
// also emits dis[i] = rsqrt(deg+1)
__global__ void k_scan_a(const int* __restrict__ cnt, int* __restrict__ rowptr,
                         int* __restrict__ bsum, float* __restrict__ dis, int N) {
    __shared__ int sh[SCAN_B];
    int t = threadIdx.x, i = blockIdx.x * SCAN_B + t;
    int v = (i < N) ? cnt[i] : 0;
    if (i < N) dis[i] = rsqrtf((float)(v + 1));   // +1 self loop
    sh[t] = v; __syncthreads();
    for (int off = 1; off < SCAN_B; off <<= 1) {
        int x = (t >= off) ? sh[t - off] : 0;
        __syncthreads();
        sh[t] += x;
        __syncthreads();
    }
    int incl = sh[t];
    if (i < N) rowptr[i] = incl - v;
    if (t == SCAN_B - 1) bsum[blockIdx.x] = incl;
}

__global__ void k_scan_b(int* bsum, int NB) {
    __shared__ int sh[512];
    int t = threadIdx.x;
    int v = (t < NB) ? bsum[t] : 0;
    sh[t] = v; __syncthreads();
    for (int off = 1; off < 512; off <<= 1) {
        int x = (t >= off) ? sh[t - off] : 0;
        __syncthreads();
        sh[t] += x;
        __syncthreads();
    }
    if (t < NB) bsum[t] = sh[t] - v;
}

__global__ void k_scan_c(int* __restrict__ rowptr, int* __restrict__ cursor,
                         const int* __restrict__ bsum, int N) {
    int i = blockIdx.x * 256 + threadIdx.x;
    if (i < N) {
        int r = rowptr[i] + bsum[blockIdx.x];
        rowptr[i] = r;
        cursor[i] = r;
    }
}

// XCD-bound fill (same queue/steal structure as k_count; second bank of 8 queues).
__global__ void k_fill(const int* __restrict__ src, const int* __restrict__ dst,
                       int* __restrict__ cursor, int* __restrict__ csrc,
                       int* __restrict__ queue, int E, int N, int nChunks) {
    __shared__ int sT;
    int xcd = my_xcd();
    for (int gi = 0; gi < 8; ++gi) {
        int gg = (xcd + gi) & 7;
        int lo = (int)((long long)gg * N / 8);
        int hi = (int)((long long)(gg + 1) * N / 8);
        for (;;) {
            if (threadIdx.x == 0) sT = atomicAdd(&queue[gg], 1);
            __syncthreads();
            int t = sT;
            __syncthreads();
            if (t >= nChunks) break;
            int base = t * FILL_CH;
            int end = base + FILL_CH; if (end > E) end = E;
            for (int e = base + threadIdx.x; e < end; e += 256) {
                int d = dst[e];
                if (d < lo || d >= hi) continue;
                int s = src[e];
                int p = atomicAdd(&cursor[d], 1);
                csrc[p] = s;
            }
        }
    }
}

// ---------- GEMM (layer 1): H[N][128](bf16) = X[N][128](fp32) @ W[128][128](fp32) ----------
__global__ __launch_bounds__(256)
void k_gemm128_a32(const float* __restrict__ X,
                   const float* __restrict__ W,
                   unsigned short* __restrict__ H, int nPairs) {
    int wave = threadIdx.x >> 6;
    int lane = threadIdx.x & 63;
    int ln = lane & 15, quad = lane >> 4;
    int c0 = (wave & 1) * 64;
    int subTile = wave >> 1;

    sh8 bh[4][4], blo[4][4];   // [nt][kt]
    #pragma unroll
    for (int nt = 0; nt < 4; ++nt) {
        int col = c0 + nt * 16 + ln;
        #pragma unroll
        for (int kt = 0; kt < 4; ++kt) {
            int k0 = kt * 32 + quad * 8;
            #pragma unroll
            for (int j = 0; j < 8; ++j) {
                short h, l;
                bfsplit(W[(k0 + j) * 128 + col], h, l);
                bh[nt][kt][j] = h; blo[nt][kt][j] = l;
            }
        }
    }

    for (int p = blockIdx.x; p < nPairs; p += gridDim.x) {
        int nodeBase = p * 32 + subTile * 16;
        const float* xrow = X + (nodeBase + ln) * 128 + quad * 8;
        sh8 ah[4], al[4];
        #pragma unroll
        for (int kt = 0; kt < 4; ++kt) {
            f4 v0 = *(const f4*)(xrow + kt * 32);
            f4 v1 = *(const f4*)(xrow + kt * 32 + 4);
            #pragma unroll
            for (int j = 0; j < 4; ++j) {
                short h, l;
                bfsplit(v0[j], h, l); ah[kt][j] = h; al[kt][j] = l;
                bfsplit(v1[j], h, l); ah[kt][j + 4] = h; al[kt][j + 4] = l;
            }
        }

        f4 acc[4] = { {0.f,0.f,0.f,0.f}, {0.f,0.f,0.f,0.f}, {0.f,0.f,0.f,0.f}, {0.f,0.f,0.f,0.f} };
        #pragma unroll
        for (int kt = 0; kt < 4; ++kt)
            #pragma unroll
            for (int nt = 0; nt < 4; ++nt) {
                acc[nt] = __builtin_amdgcn_mfma_f32_16x16x32_bf16(ah[kt], bh[nt][kt], acc[nt], 0, 0, 0);
                acc[nt] = __builtin_amdgcn_mfma_f32_16x16x32_bf16(ah[kt], blo[nt][kt], acc[nt], 0, 0, 0);
                acc[nt] = __builtin_amdgcn_mfma_f32_16x16x32_bf16(al[kt], bh[nt][kt], acc[nt], 0, 0, 0);
            }

        #pragma unroll
        for (int nt = 0; nt < 4; ++nt) {
            int col = c0 + nt * 16 + ln;
            #pragma unroll
            for (int r = 0; r < 4; ++r)
                H[(nodeBase + quad * 4 + r) * 128 + col] = f2bf(acc[nt][r]);
        }
    }
}

// ---------- GEMM (layers 2,3): H(bf16) = X(bf16) @ W(fp32, split) ----------
__global__ __launch_bounds__(256)
void k_gemm128_a16(const unsigned short* __restrict__ X,
                   const float* __restrict__ W,
                   unsigned short* __restrict__ H, int nPairs) {
    int wave = threadIdx.x >> 6;
    int lane = threadIdx.x & 63;
    int ln = lane & 15, quad = lane >> 4;
    int c0 = (wave & 1) * 64;
    int subTile = wave >> 1;

    sh8 bh[4][4], blo[4][4];
    #pragma unroll
    for (int nt = 0; nt < 4; ++nt) {
        int col = c0 + nt * 16 + ln;
        #pragma unroll
        for (int kt = 0; kt < 4; ++kt) {
            int k0 = kt * 32 + quad * 8;
            #pragma unroll
            for (int j = 0; j < 8; ++j) {
                short h, l;
                bfsplit(W[(k0 + j) * 128 + col], h, l);
                bh[nt][kt][j] = h; blo[nt][kt][j] = l;
            }
        }
    }

    for (int p = blockIdx.x; p < nPairs; p += gridDim.x) {
        int nodeBase = p * 32 + subTile * 16;
        const unsigned short* xrow = X + (nodeBase + ln) * 128 + quad * 8;
        sh8 a[4];
        #pragma unroll
        for (int kt = 0; kt < 4; ++kt) a[kt] = *(const sh8*)(xrow + kt * 32);

        f4 acc[4] = { {0.f,0.f,0.f,0.f}, {0.f,0.f,0.f,0.f}, {0.f,0.f,0.f,0.f}, {0.f,0.f,0.f,0.f} };
        #pragma unroll
        for (int kt = 0; kt < 4; ++kt)
            #pragma unroll
            for (int nt = 0; nt < 4; ++nt) {
                acc[nt] = __builtin_amdgcn_mfma_f32_16x16x32_bf16(a[kt], bh[nt][kt], acc[nt], 0, 0, 0);
                acc[nt] = __builtin_amdgcn_mfma_f32_16x16x32_bf16(a[kt], blo[nt][kt], acc[nt], 0, 0, 0);
            }

        #pragma unroll
        for (int nt = 0; nt < 4; ++nt) {
            int col = c0 + nt * 16 + ln;
            #pragma unroll
            for (int r = 0; r < 4; ++r)
                H[(nodeBase + quad * 4 + r) * 128 + col] = f2bf(acc[nt][r]);
        }
    }
}

// ---------- Aggregation (pair-row): one wave per node, 2 edges per gather step ----------
// Half h = lane>>5 handles edges i+2q+h; 32 lanes x 8B (4 bf16 feats) cover one 256B row.
// fp32 accum (4/lane); halves combined with one shfl at the end.
__global__ __launch_bounds__(256)
void k_agg(const unsigned short* __restrict__ H,
           unsigned short* __restrict__ O,
           const float* __restrict__ dis,
           const int* __restrict__ rowptr,
           const int* __restrict__ cnt,
           const int* __restrict__ csrc,
           const float* __restrict__ bias,
           int relu, int N) {
    int n = (blockIdx.x * 256 + threadIdx.x) >> 6;
    int lane = threadIdx.x & 63;
    if (n >= N) return;
    int half = lane >> 5;
    int sl = lane & 31;           // covers feats sl*4 .. sl*4+3

    float dn = dis[n];
    float a0 = 0.f, a1 = 0.f, a2 = 0.f, a3 = 0.f;

    if (half == 0) {              // self loop: only half 0 (avoid double count)
        uint2 v = *(const uint2*)(H + (size_t)n * 128 + sl * 4);
        float w = dn * dn;
        a0 += w * bf2f((unsigned short)v.x);
        a1 += w * bf2f((unsigned short)(v.x >> 16));
        a2 += w * bf2f((unsigned short)v.y);
        a3 += w * bf2f((unsigned short)(v.y >> 16));
    }

    int start = rowptr[n];
    int e = cnt[n];
    int ePair = e & ~1;
    int i = 0;
    // 4 pairs (8 edges) per iteration: 4 independent gathers in flight per half
    for (; i + 8 <= ePair; i += 8) {
        int s[4];
        #pragma unroll
        for (int q = 0; q < 4; ++q) s[q] = csrc[start + i + 2 * q + half];
        uint2 v[4];
        #pragma unroll
        for (int q = 0; q < 4; ++q) v[q] = *(const uint2*)(H + (size_t)s[q] * 128 + sl * 4);
        float w[4];
        #pragma unroll
        for (int q = 0; q < 4; ++q) w[q] = dis[s[q]] * dn;
        #pragma unroll
        for (int q = 0; q < 4; ++q) {
            a0 += w[q] * bf2f((unsigned short)v[q].x);
            a1 += w[q] * bf2f((unsigned short)(v[q].x >> 16));
            a2 += w[q] * bf2f((unsigned short)v[q].y);
            a3 += w[q] * bf2f((unsigned short)(v[q].y >> 16));
        }
    }
    for (; i < ePair; i += 2) {
        int s0 = csrc[start + i + half];
        uint2 v = *(const uint2*)(H + (size_t)s0 * 128 + sl * 4);
        float w = dis[s0] * dn;
        a0 += w * bf2f((unsigned short)v.x);
        a1 += w * bf2f((unsigned short)(v.x >> 16));
        a2 += w * bf2f((unsigned short)v.y);
        a3 += w * bf2f((unsigned short)(v.y >> 16));
    }
    if ((e & 1) && half == 0) {   // odd tail edge on half 0
        int s0 = csrc[start + e - 1];
        uint2 v = *(const uint2*)(H + (size_t)s0 * 128 + sl * 4);
        float w = dis[s0] * dn;
        a0 += w * bf2f((unsigned short)v.x);
        a1 += w * bf2f((unsigned short)(v.x >> 16));
        a2 += w * bf2f((unsigned short)v.y);
        a3 += w * bf2f((unsigned short)(v.y >> 16));
    }

    // combine halves: lane L += lane L+32
    a0 += __shfl_down(a0, 32);
    a1 += __shfl_down(a1, 32);
    a2 += __shfl_down(a2, 32);
    a3 += __shfl_down(a3, 32);

    if (half == 0) {
        int c = sl * 4;
        a0 += bias[c];
        a1 += bias[c + 1];
        a2 += bias[c + 2];
        a3 += bias[c + 3];
        if (relu) {
            a0 = fmaxf(a0, 0.f); a1 = fmaxf(a1, 0.f);
            a2 = fmaxf(a2, 0.f); a3 = fmaxf(a3, 0.f);
        }
        uint2 ov;
        ov.x = (unsigned int)f2bf(a0) | ((unsigned int)f2bf(a1) << 16);
        ov.y = (unsigned int)f2bf(a2) | ((unsigned int)f2bf(a3) << 16);
        *(uint2*)(O + (size_t)n * 128 + c) = ov;
    }
}

// ---------- Final head: OUT[N][40](fp32) = X(bf16) @ Wl(fp32 split) + bl ----------
__global__ __launch_bounds__(256)
void k_gemm_final(const unsigned short* __restrict__ X,
                  const float* __restrict__ W,     // [128][40]
                  const float* __restrict__ bl,    // [40]
                  float* __restrict__ OUT, int nTiles) {
    int wave = threadIdx.x >> 6;
    int lane = threadIdx.x & 63;
    int ln = lane & 15, quad = lane >> 4;
    int tile = blockIdx.x * 4 + wave;
    if (tile >= nTiles) return;

    sh8 bh[3][4], blo[3][4];
    #pragma unroll
    for (int nt = 0; nt < 3; ++nt) {
        int col = nt * 16 + ln;
        bool valid = (col < 40);
        #pragma unroll
        for (int kt = 0; kt < 4; ++kt) {
            int k0 = kt * 32 + quad * 8;
            #pragma unroll
            for (int j = 0; j < 8; ++j) {
                short h = 0, l = 0;
                if (valid) bfsplit(W[(k0 + j) * 40 + col], h, l);
                bh[nt][kt][j] = h; blo[nt][kt][j] = l;
            }
        }
    }

    int nodeBase = tile * 16;
    const unsigned short* xrow = X + (nodeBase + ln) * 128 + quad * 8;
    sh8 a[4];
    #pragma unroll
    for (int kt = 0; kt < 4; ++kt) a[kt] = *(const sh8*)(xrow + kt * 32);

    f4 acc[3] = { {0.f,0.f,0.f,0.f}, {0.f,0.f,0.f,0.f}, {0.f,0.f,0.f,0.f} };
    #pragma unroll
    for (int kt = 0; kt < 4; ++kt)
        #pragma unroll
        for (int nt = 0; nt < 3; ++nt) {
            acc[nt] = __builtin_amdgcn_mfma_f32_16x16x32_bf16(a[kt], bh[nt][kt], acc[nt], 0, 0, 0);
            acc[nt] = __builtin_amdgcn_mfma_f32_16x16x32_bf16(a[kt], blo[nt][kt], acc[nt], 0, 0, 0);
        }

    #pragma unroll
    for (int nt = 0; nt < 3; ++nt) {
        int col = nt * 16 + ln;
        if (col < 40) {
            float bv = bl[col];
            #pragma unroll
            for (int r = 0; r < 4; ++r)
                OUT[(nodeBase + quad * 4 + r) * 40 + col] = acc[nt][r] + bv;
        }
    }
}

// ---------- launch ----------
extern "C" void kernel_launch(void* const* d_in, const int* in_sizes, int n_in,
                              void* d_out, int out_size, void* d_ws, size_t ws_size,
                              hipStream_t stream) {
    const float* x  = (const float*)d_in[0];
    const int*   ei = (const int*)d_in[1];
    const float* W1 = (const float*)d_in[2];
    const float* b1 = (const float*)d_in[3];
    const float* W2 = (const float*)d_in[4];
    const float* b2 = (const float*)d_in[5];
    const float* W3 = (const float*)d_in[6];
    const float* b3 = (const float*)d_in[7];
    const float* Wl = (const float*)d_in[8];
    const float* bl = (const float*)d_in[9];

    const int N = in_sizes[0] / 128;   // 100000
    const int E = in_sizes[1] / 2;     // 1600000
    const int* srcIdx = ei;
    const int* dstIdx = ei + E;

    char* ws = (char*)d_ws;
    size_t off = 0;
    auto alloc = [&](size_t bytes) { void* p = ws + off; off += (bytes + 511) & ~(size_t)511; return p; };
    int*   cnt     = (int*)  alloc((size_t)N * 4);
    int*   rowptr  = (int*)  alloc((size_t)N * 4);
    int*   cursor  = (int*)  alloc((size_t)N * 4);
    float* dis     = (float*)alloc((size_t)N * 4);
    int*   bsum    = (int*)  alloc(512 * 4);
    int*   queues  = (int*)  alloc(16 * 4);          // [0..7] count, [8..15] fill
    int*   csrc    = (int*)  alloc((size_t)E * 4);
    unsigned short* h0 = (unsigned short*)alloc((size_t)N * 128 * 2);
    unsigned short* h1 = (unsigned short*)alloc((size_t)N * 128 * 2);

    const int gN = (N + 255) / 256;           // 391
    const int nPairs = N / 32;                // 3125
    const int nTiles = N / 16;                // 6250
    const int gAgg = (N * 64) / 256;          // 25000
    const int gPart = 1024;
    const int nChunks = (E + FILL_CH - 1) / FILL_CH;

    // CSR build (count/fill bound to actual XCD via work queues)
    k_zero_cnt<<<gN, 256, 0, stream>>>(cnt, queues, N);
    k_count<<<gPart, 256, 0, stream>>>(dstIdx, cnt, queues, E, N, nChunks);
    k_scan_a<<<gN, 256, 0, stream>>>(cnt, rowptr, bsum, dis, N);
    k_scan_b<<<1, 512, 0, stream>>>(bsum, gN);
    k_scan_c<<<gN, 256, 0, stream>>>(rowptr, cursor, bsum, N);
    k_fill<<<gPart, 256, 0, stream>>>(srcIdx, dstIdx, cursor, csrc, queues + 8, E, N, nChunks);

    // Layer 1
    k_gemm128_a32<<<768, 256, 0, stream>>>(x, W1, h0, nPairs);
    k_agg<<<gAgg, 256, 0, stream>>>(h0, h1, dis, rowptr, cnt, csrc, b1, 1, N);
    // Layer 2
    k_gemm128_a16<<<768, 256, 0, stream>>>(h1, W2, h0, nPairs);
    k_agg<<<gAgg, 256, 0, stream>>>(h0, h1, dis, rowptr, cnt, csrc, b2, 1, N);
    // Layer 3 (no relu)
    k_gemm128_a16<<<768, 256, 0, stream>>>(h1, W3, h0, nPairs);
    k_agg<<<gAgg, 256, 0, stream>>>(h0, h1, dis, rowptr, cnt, csrc, b3, 0, N);
    // Head
    k_gemm_final<<<(nTiles + 3) / 4, 256, 0, stream>>>(h1, Wl, bl, (float*)d_out, nTiles);
}

// Round 7
// 611.827 us; speedup vs baseline: 1.2621x; 1.2621x over previous
//
#include <hip/hip_runtime.h>

// ---------- types & helpers ----------
typedef __attribute__((ext_vector_type(8))) short sh8;   // 8 x bf16 (4 VGPRs)
typedef __attribute__((ext_vector_type(4))) float f4;    // MFMA accum / float4

__device__ __forceinline__ float bf2f(unsigned short u) {
    union { unsigned int u; float f; } c; c.u = ((unsigned int)u) << 16; return c.f;
}
__device__ __forceinline__ unsigned short f2bf(float f) {
    union { float f; unsigned int u; } c; c.f = f;
    unsigned int x = c.u;
    unsigned int r = (x + 0x7fffu + ((x >> 16) & 1u)) >> 16;   // RNE
    return (unsigned short)r;
}
__device__ __forceinline__ void bfsplit(float x, short& hi, short& lo) {
    unsigned short h = f2bf(x);
    float r = x - bf2f(h);
    hi = (short)h;
    lo = (short)f2bf(r);
}

// ---------- CSR build ----------
__global__ void k_zero_cnt(int* cnt, int N) {
    int i = blockIdx.x * 256 + threadIdx.x;
    if (i < N) cnt[i] = 0;
}

// dst-range partitioned count (8 groups round-robin over blocks). Edge-list reads are
// NON-TEMPORAL so the 8x re-read stream doesn't evict L2-resident cnt lines.
__global__ void k_count(const int* __restrict__ dst, int* __restrict__ cnt, int E, int N) {
    int g = blockIdx.x & 7;
    int j = blockIdx.x >> 3;
    int nb = gridDim.x >> 3;
    int lo = (int)((long long)g * N / 8);
    int hi = (int)((long long)(g + 1) * N / 8);
    for (int e = j * 256 + threadIdx.x; e < E; e += nb * 256) {
        int d = __builtin_nontemporal_load(&dst[e]);
        if (d >= lo && d < hi) atomicAdd(&cnt[d], 1);
    }
}

#define SCAN_B 256
// also emits dis[i] = rsqrt(deg+1)
__global__ void k_scan_a(const int* __restrict__ cnt, int* __restrict__ rowptr,
                         int* __restrict__ bsum, float* __restrict__ dis, int N) {
    __shared__ int sh[SCAN_B];
    int t = threadIdx.x, i = blockIdx.x * SCAN_B + t;
    int v = (i < N) ? cnt[i] : 0;
    if (i < N) dis[i] = rsqrtf((float)(v + 1));   // +1 self loop
    sh[t] = v; __syncthreads();
    for (int off = 1; off < SCAN_B; off <<= 1) {
        int x = (t >= off) ? sh[t - off] : 0;
        __syncthreads();
        sh[t] += x;
        __syncthreads();
    }
    int incl = sh[t];
    if (i < N) rowptr[i] = incl - v;
    if (t == SCAN_B - 1) bsum[blockIdx.x] = incl;
}

__global__ void k_scan_b(int* bsum, int NB) {
    __shared__ int sh[512];
    int t = threadIdx.x;
    int v = (t < NB) ? bsum[t] : 0;
    sh[t] = v; __syncthreads();
    for (int off = 1; off < 512; off <<= 1) {
        int x = (t >= off) ? sh[t - off] : 0;
        __syncthreads();
        sh[t] += x;
        __syncthreads();
    }
    if (t < NB) bsum[t] = sh[t] - v;
}

__global__ void k_scan_c(int* __restrict__ rowptr, int* __restrict__ cursor,
                         const int* __restrict__ bsum, int N) {
    int i = blockIdx.x * 256 + threadIdx.x;
    if (i < N) {
        int r = rowptr[i] + bsum[blockIdx.x];
        rowptr[i] = r;
        cursor[i] = r;
    }
}

// dst-range partitioned fill. NT edge-list reads keep the dirty csrc scatter lines
// resident in L2 until all ~16 entries of a line have merged.
__global__ void k_fill(const int* __restrict__ src, const int* __restrict__ dst,
                       int* __restrict__ cursor, int* __restrict__ csrc, int E, int N) {
    int g = blockIdx.x & 7;
    int j = blockIdx.x >> 3;
    int nb = gridDim.x >> 3;
    int lo = (int)((long long)g * N / 8);
    int hi = (int)((long long)(g + 1) * N / 8);
    for (int e = j * 256 + threadIdx.x; e < E; e += nb * 256) {
        int d = __builtin_nontemporal_load(&dst[e]);
        if (d < lo || d >= hi) continue;
        int s = __builtin_nontemporal_load(&src[e]);
        if ((unsigned)s >= (unsigned)N) continue;
        int p = atomicAdd(&cursor[d], 1);
        csrc[p] = s;
    }
}

// ---------- GEMM (layer 1): H[N][128](bf16) = X[N][128](fp32) @ W[128][128](fp32) ----------
__global__ __launch_bounds__(256)
void k_gemm128_a32(const float* __restrict__ X,
                   const float* __restrict__ W,
                   unsigned short* __restrict__ H, int nPairs) {
    int wave = threadIdx.x >> 6;
    int lane = threadIdx.x & 63;
    int ln = lane & 15, quad = lane >> 4;
    int c0 = (wave & 1) * 64;
    int subTile = wave >> 1;

    sh8 bh[4][4], blo[4][4];   // [nt][kt]
    #pragma unroll
    for (int nt = 0; nt < 4; ++nt) {
        int col = c0 + nt * 16 + ln;
        #pragma unroll
        for (int kt = 0; kt < 4; ++kt) {
            int k0 = kt * 32 + quad * 8;
            #pragma unroll
            for (int j = 0; j < 8; ++j) {
                short h, l;
                bfsplit(W[(k0 + j) * 128 + col], h, l);
                bh[nt][kt][j] = h; blo[nt][kt][j] = l;
            }
        }
    }

    for (int p = blockIdx.x; p < nPairs; p += gridDim.x) {
        int nodeBase = p * 32 + subTile * 16;
        const float* xrow = X + (nodeBase + ln) * 128 + quad * 8;
        sh8 ah[4], al[4];
        #pragma unroll
        for (int kt = 0; kt < 4; ++kt) {
            f4 v0 = *(const f4*)(xrow + kt * 32);
            f4 v1 = *(const f4*)(xrow + kt * 32 + 4);
            #pragma unroll
            for (int j = 0; j < 4; ++j) {
                short h, l;
                bfsplit(v0[j], h, l); ah[kt][j] = h; al[kt][j] = l;
                bfsplit(v1[j], h, l); ah[kt][j + 4] = h; al[kt][j + 4] = l;
            }
        }

        f4 acc[4] = { {0.f,0.f,0.f,0.f}, {0.f,0.f,0.f,0.f}, {0.f,0.f,0.f,0.f}, {0.f,0.f,0.f,0.f} };
        #pragma unroll
        for (int kt = 0; kt < 4; ++kt)
            #pragma unroll
            for (int nt = 0; nt < 4; ++nt) {
                acc[nt] = __builtin_amdgcn_mfma_f32_16x16x32_bf16(ah[kt], bh[nt][kt], acc[nt], 0, 0, 0);
                acc[nt] = __builtin_amdgcn_mfma_f32_16x16x32_bf16(ah[kt], blo[nt][kt], acc[nt], 0, 0, 0);
                acc[nt] = __builtin_amdgcn_mfma_f32_16x16x32_bf16(al[kt], bh[nt][kt], acc[nt], 0, 0, 0);
            }

        #pragma unroll
        for (int nt = 0; nt < 4; ++nt) {
            int col = c0 + nt * 16 + ln;
            #pragma unroll
            for (int r = 0; r < 4; ++r)
                H[(nodeBase + quad * 4 + r) * 128 + col] = f2bf(acc[nt][r]);
        }
    }
}

// ---------- GEMM (layers 2,3): H(bf16) = X(bf16) @ W(fp32, split) ----------
__global__ __launch_bounds__(256)
void k_gemm128_a16(const unsigned short* __restrict__ X,
                   const float* __restrict__ W,
                   unsigned short* __restrict__ H, int nPairs) {
    int wave = threadIdx.x >> 6;
    int lane = threadIdx.x & 63;
    int ln = lane & 15, quad = lane >> 4;
    int c0 = (wave & 1) * 64;
    int subTile = wave >> 1;

    sh8 bh[4][4], blo[4][4];
    #pragma unroll
    for (int nt = 0; nt < 4; ++nt) {
        int col = c0 + nt * 16 + ln;
        #pragma unroll
        for (int kt = 0; kt < 4; ++kt) {
            int k0 = kt * 32 + quad * 8;
            #pragma unroll
            for (int j = 0; j < 8; ++j) {
                short h, l;
                bfsplit(W[(k0 + j) * 128 + col], h, l);
                bh[nt][kt][j] = h; blo[nt][kt][j] = l;
            }
        }
    }

    for (int p = blockIdx.x; p < nPairs; p += gridDim.x) {
        int nodeBase = p * 32 + subTile * 16;
        const unsigned short* xrow = X + (nodeBase + ln) * 128 + quad * 8;
        sh8 a[4];
        #pragma unroll
        for (int kt = 0; kt < 4; ++kt) a[kt] = *(const sh8*)(xrow + kt * 32);

        f4 acc[4] = { {0.f,0.f,0.f,0.f}, {0.f,0.f,0.f,0.f}, {0.f,0.f,0.f,0.f}, {0.f,0.f,0.f,0.f} };
        #pragma unroll
        for (int kt = 0; kt < 4; ++kt)
            #pragma unroll
            for (int nt = 0; nt < 4; ++nt) {
                acc[nt] = __builtin_amdgcn_mfma_f32_16x16x32_bf16(a[kt], bh[nt][kt], acc[nt], 0, 0, 0);
                acc[nt] = __builtin_amdgcn_mfma_f32_16x16x32_bf16(a[kt], blo[nt][kt], acc[nt], 0, 0, 0);
            }

        #pragma unroll
        for (int nt = 0; nt < 4; ++nt) {
            int col = c0 + nt * 16 + ln;
            #pragma unroll
            for (int r = 0; r < 4; ++r)
                H[(nodeBase + quad * 4 + r) * 128 + col] = f2bf(acc[nt][r]);
        }
    }
}

// ---------- Aggregation (pair-row): one wave per node, 2 edges per gather step ----------
// Half h = lane>>5 handles edges i+2q+h; 32 lanes x 8B (4 bf16 feats) cover one 256B row.
// fp32 accum (4/lane); halves combined with one shfl at the end. csrc reads NT (read-once).
__global__ __launch_bounds__(256)
void k_agg(const unsigned short* __restrict__ H,
           unsigned short* __restrict__ O,
           const float* __restrict__ dis,
           const int* __restrict__ rowptr,
           const int* __restrict__ cnt,
           const int* __restrict__ csrc,
           const float* __restrict__ bias,
           int relu, int N) {
    int n = (blockIdx.x * 256 + threadIdx.x) >> 6;
    int lane = threadIdx.x & 63;
    if (n >= N) return;
    int half = lane >> 5;
    int sl = lane & 31;           // covers feats sl*4 .. sl*4+3

    float dn = dis[n];
    float a0 = 0.f, a1 = 0.f, a2 = 0.f, a3 = 0.f;

    if (half == 0) {              // self loop: only half 0 (avoid double count)
        uint2 v = *(const uint2*)(H + (size_t)n * 128 + sl * 4);
        float w = dn * dn;
        a0 += w * bf2f((unsigned short)v.x);
        a1 += w * bf2f((unsigned short)(v.x >> 16));
        a2 += w * bf2f((unsigned short)v.y);
        a3 += w * bf2f((unsigned short)(v.y >> 16));
    }

    int start = rowptr[n];
    int e = cnt[n];
    int ePair = e & ~1;
    int i = 0;
    for (; i + 8 <= ePair; i += 8) {
        int s[4];
        #pragma unroll
        for (int q = 0; q < 4; ++q) s[q] = __builtin_nontemporal_load(&csrc[start + i + 2 * q + half]);
        uint2 v[4];
        #pragma unroll
        for (int q = 0; q < 4; ++q) v[q] = *(const uint2*)(H + (size_t)s[q] * 128 + sl * 4);
        float w[4];
        #pragma unroll
        for (int q = 0; q < 4; ++q) w[q] = dis[s[q]] * dn;
        #pragma unroll
        for (int q = 0; q < 4; ++q) {
            a0 += w[q] * bf2f((unsigned short)v[q].x);
            a1 += w[q] * bf2f((unsigned short)(v[q].x >> 16));
            a2 += w[q] * bf2f((unsigned short)v[q].y);
            a3 += w[q] * bf2f((unsigned short)(v[q].y >> 16));
        }
    }
    for (; i < ePair; i += 2) {
        int s0 = csrc[start + i + half];
        uint2 v = *(const uint2*)(H + (size_t)s0 * 128 + sl * 4);
        float w = dis[s0] * dn;
        a0 += w * bf2f((unsigned short)v.x);
        a1 += w * bf2f((unsigned short)(v.x >> 16));
        a2 += w * bf2f((unsigned short)v.y);
        a3 += w * bf2f((unsigned short)(v.y >> 16));
    }
    if ((e & 1) && half == 0) {   // odd tail edge on half 0
        int s0 = csrc[start + e - 1];
        uint2 v = *(const uint2*)(H + (size_t)s0 * 128 + sl * 4);
        float w = dis[s0] * dn;
        a0 += w * bf2f((unsigned short)v.x);
        a1 += w * bf2f((unsigned short)(v.x >> 16));
        a2 += w * bf2f((unsigned short)v.y);
        a3 += w * bf2f((unsigned short)(v.y >> 16));
    }

    // combine halves: lane L += lane L+32
    a0 += __shfl_down(a0, 32);
    a1 += __shfl_down(a1, 32);
    a2 += __shfl_down(a2, 32);
    a3 += __shfl_down(a3, 32);

    if (half == 0) {
        int c = sl * 4;
        a0 += bias[c];
        a1 += bias[c + 1];
        a2 += bias[c + 2];
        a3 += bias[c + 3];
        if (relu) {
            a0 = fmaxf(a0, 0.f); a1 = fmaxf(a1, 0.f);
            a2 = fmaxf(a2, 0.f); a3 = fmaxf(a3, 0.f);
        }
        uint2 ov;
        ov.x = (unsigned int)f2bf(a0) | ((unsigned int)f2bf(a1) << 16);
        ov.y = (unsigned int)f2bf(a2) | ((unsigned int)f2bf(a3) << 16);
        *(uint2*)(O + (size_t)n * 128 + c) = ov;
    }
}

// ---------- Final head: OUT[N][40](fp32) = X(bf16) @ Wl(fp32 split) + bl ----------
__global__ __launch_bounds__(256)
void k_gemm_final(const unsigned short* __restrict__ X,
                  const float* __restrict__ W,     // [128][40]
                  const float* __restrict__ bl,    // [40]
                  float* __restrict__ OUT, int nTiles) {
    int wave = threadIdx.x >> 6;
    int lane = threadIdx.x & 63;
    int ln = lane & 15, quad = lane >> 4;
    int tile = blockIdx.x * 4 + wave;
    if (tile >= nTiles) return;

    sh8 bh[3][4], blo[3][4];
    #pragma unroll
    for (int nt = 0; nt < 3; ++nt) {
        int col = nt * 16 + ln;
        bool valid = (col < 40);
        #pragma unroll
        for (int kt = 0; kt < 4; ++kt) {
            int k0 = kt * 32 + quad * 8;
            #pragma unroll
            for (int j = 0; j < 8; ++j) {
                short h = 0, l = 0;
                if (valid) bfsplit(W[(k0 + j) * 40 + col], h, l);
                bh[nt][kt][j] = h; blo[nt][kt][j] = l;
            }
        }
    }

    int nodeBase = tile * 16;
    const unsigned short* xrow = X + (nodeBase + ln) * 128 + quad * 8;
    sh8 a[4];
    #pragma unroll
    for (int kt = 0; kt < 4; ++kt) a[kt] = *(const sh8*)(xrow + kt * 32);

    f4 acc[3] = { {0.f,0.f,0.f,0.f}, {0.f,0.f,0.f,0.f}, {0.f,0.f,0.f,0.f} };
    #pragma unroll
    for (int kt = 0; kt < 4; ++kt)
        #pragma unroll
        for (int nt = 0; nt < 3; ++nt) {
            acc[nt] = __builtin_amdgcn_mfma_f32_16x16x32_bf16(a[kt], bh[nt][kt], acc[nt], 0, 0, 0);
            acc[nt] = __builtin_amdgcn_mfma_f32_16x16x32_bf16(a[kt], blo[nt][kt], acc[nt], 0, 0, 0);
        }

    #pragma unroll
    for (int nt = 0; nt < 3; ++nt) {
        int col = nt * 16 + ln;
        if (col < 40) {
            float bv = bl[col];
            #pragma unroll
            for (int r = 0; r < 4; ++r)
                OUT[(nodeBase + quad * 4 + r) * 40 + col] = acc[nt][r] + bv;
        }
    }
}

// ---------- launch ----------
extern "C" void kernel_launch(void* const* d_in, const int* in_sizes, int n_in,
                              void* d_out, int out_size, void* d_ws, size_t ws_size,
                              hipStream_t stream) {
    const float* x  = (const float*)d_in[0];
    const int*   ei = (const int*)d_in[1];
    const float* W1 = (const float*)d_in[2];
    const float* b1 = (const float*)d_in[3];
    const float* W2 = (const float*)d_in[4];
    const float* b2 = (const float*)d_in[5];
    const float* W3 = (const float*)d_in[6];
    const float* b3 = (const float*)d_in[7];
    const float* Wl = (const float*)d_in[8];
    const float* bl = (const float*)d_in[9];

    const int N = in_sizes[0] / 128;   // 100000
    const int E = in_sizes[1] / 2;     // 1600000
    const int* srcIdx = ei;
    const int* dstIdx = ei + E;

    char* ws = (char*)d_ws;
    size_t off = 0;
    auto alloc = [&](size_t bytes) { void* p = ws + off; off += (bytes + 511) & ~(size_t)511; return p; };
    int*   cnt     = (int*)  alloc((size_t)N * 4);
    int*   rowptr  = (int*)  alloc((size_t)N * 4);
    int*   cursor  = (int*)  alloc((size_t)N * 4);
    float* dis     = (float*)alloc((size_t)N * 4);
    int*   bsum    = (int*)  alloc(512 * 4);
    int*   csrc    = (int*)  alloc((size_t)E * 4);
    unsigned short* h0 = (unsigned short*)alloc((size_t)N * 128 * 2);
    unsigned short* h1 = (unsigned short*)alloc((size_t)N * 128 * 2);

    const int gN = (N + 255) / 256;           // 391
    const int nPairs = N / 32;                // 3125
    const int nTiles = N / 16;                // 6250
    const int gAgg = (N * 64) / 256;          // 25000
    const int gPart = 1024;                   // 8 dst-range groups x 128 blocks

    // CSR build
    k_zero_cnt<<<gN, 256, 0, stream>>>(cnt, N);
    k_count<<<gPart, 256, 0, stream>>>(dstIdx, cnt, E, N);
    k_scan_a<<<gN, 256, 0, stream>>>(cnt, rowptr, bsum, dis, N);
    k_scan_b<<<1, 512, 0, stream>>>(bsum, gN);
    k_scan_c<<<gN, 256, 0, stream>>>(rowptr, cursor, bsum, N);
    k_fill<<<gPart, 256, 0, stream>>>(srcIdx, dstIdx, cursor, csrc, E, N);

    // Layer 1
    k_gemm128_a32<<<768, 256, 0, stream>>>(x, W1, h0, nPairs);
    k_agg<<<gAgg, 256, 0, stream>>>(h0, h1, dis, rowptr, cnt, csrc, b1, 1, N);
    // Layer 2
    k_gemm128_a16<<<768, 256, 0, stream>>>(h1, W2, h0, nPairs);
    k_agg<<<gAgg, 256, 0, stream>>>(h0, h1, dis, rowptr, cnt, csrc, b2, 1, N);
    // Layer 3 (no relu)
    k_gemm128_a16<<<768, 256, 0, stream>>>(h1, W3, h0, nPairs);
    k_agg<<<gAgg, 256, 0, stream>>>(h0, h1, dis, rowptr, cnt, csrc, b3, 0, N);
    // Head
    k_gemm_final<<<(nTiles + 3) / 4, 256, 0, stream>>>(h1, Wl, bl, (float*)d_out, nTiles);
}

// Round 8
// 539.044 us; speedup vs baseline: 1.4325x; 1.1350x over previous
//
#include <hip/hip_runtime.h>

// ---------- types & helpers ----------
typedef __attribute__((ext_vector_type(8))) short sh8;   // 8 x bf16 (4 VGPRs)
typedef __attribute__((ext_vector_type(4))) float f4;    // MFMA accum / float4

__device__ __forceinline__ float bf2f(unsigned short u) {
    union { unsigned int u; float f; } c; c.u = ((unsigned int)u) << 16; return c.f;
}
__device__ __forceinline__ unsigned short f2bf(float f) {
    union { float f; unsigned int u; } c; c.f = f;
    unsigned int x = c.u;
    unsigned int r = (x + 0x7fffu + ((x >> 16) & 1u)) >> 16;   // RNE
    return (unsigned short)r;
}
__device__ __forceinline__ void bfsplit(float x, short& hi, short& lo) {
    unsigned short h = f2bf(x);
    float r = x - bf2f(h);
    hi = (short)h;
    lo = (short)f2bf(r);
}

// ---------- CSR build ----------
__global__ void k_zero_cnt(int* cnt, int N) {
    int i = blockIdx.x * 256 + threadIdx.x;
    if (i < N) cnt[i] = 0;
}

// Unpartitioned count: one pass, int4 loads (4 edges/lane/inst). Atomics scatter to the
// 400KB cnt array; no scatter *stores*, so no partitioning needed.
__global__ void k_count(const int* __restrict__ dst, int* __restrict__ cnt, int E, int N) {
    int E4 = E >> 2;
    for (int i = blockIdx.x * 256 + threadIdx.x; i < E4; i += gridDim.x * 256) {
        int4 d = ((const int4*)dst)[i];
        if ((unsigned)d.x < (unsigned)N) atomicAdd(&cnt[d.x], 1);
        if ((unsigned)d.y < (unsigned)N) atomicAdd(&cnt[d.y], 1);
        if ((unsigned)d.z < (unsigned)N) atomicAdd(&cnt[d.z], 1);
        if ((unsigned)d.w < (unsigned)N) atomicAdd(&cnt[d.w], 1);
    }
    if (blockIdx.x == 0) {   // remainder edges
        for (int e = (E4 << 2) + threadIdx.x; e < E; e += 256) {
            int d = dst[e];
            if ((unsigned)d < (unsigned)N) atomicAdd(&cnt[d], 1);
        }
    }
}

#define SCAN_B 256
// also emits dis[i] = rsqrt(deg+1)
__global__ void k_scan_a(const int* __restrict__ cnt, int* __restrict__ rowptr,
                         int* __restrict__ bsum, float* __restrict__ dis, int N) {
    __shared__ int sh[SCAN_B];
    int t = threadIdx.x, i = blockIdx.x * SCAN_B + t;
    int v = (i < N) ? cnt[i] : 0;
    if (i < N) dis[i] = rsqrtf((float)(v + 1));   // +1 self loop
    sh[t] = v; __syncthreads();
    for (int off = 1; off < SCAN_B; off <<= 1) {
        int x = (t >= off) ? sh[t - off] : 0;
        __syncthreads();
        sh[t] += x;
        __syncthreads();
    }
    int incl = sh[t];
    if (i < N) rowptr[i] = incl - v;
    if (t == SCAN_B - 1) bsum[blockIdx.x] = incl;
}

__global__ void k_scan_b(int* bsum, int NB) {
    __shared__ int sh[512];
    int t = threadIdx.x;
    int v = (t < NB) ? bsum[t] : 0;
    sh[t] = v; __syncthreads();
    for (int off = 1; off < 512; off <<= 1) {
        int x = (t >= off) ? sh[t - off] : 0;
        __syncthreads();
        sh[t] += x;
        __syncthreads();
    }
    if (t < NB) bsum[t] = sh[t] - v;
}

__global__ void k_scan_c(int* __restrict__ rowptr, int* __restrict__ cursor,
                         const int* __restrict__ bsum, int N) {
    int i = blockIdx.x * 256 + threadIdx.x;
    if (i < N) {
        int r = rowptr[i] + bsum[blockIdx.x];
        rowptr[i] = r;
        cursor[i] = r;
    }
}

// dst-range partitioned fill (8 groups round-robin), plain (cached) int4 dst reads.
__global__ void k_fill(const int* __restrict__ src, const int* __restrict__ dst,
                       int* __restrict__ cursor, int* __restrict__ csrc, int E, int N) {
    int g = blockIdx.x & 7;
    int j = blockIdx.x >> 3;
    int nb = gridDim.x >> 3;
    int lo = (int)((long long)g * N / 8);
    int hi = (int)((long long)(g + 1) * N / 8);
    int E4 = E >> 2;
    for (int i = j * 256 + threadIdx.x; i < E4; i += nb * 256) {
        int4 d4 = ((const int4*)dst)[i];
        int e = i << 2;
        #pragma unroll
        for (int q = 0; q < 4; ++q) {
            int d = (q == 0) ? d4.x : (q == 1) ? d4.y : (q == 2) ? d4.z : d4.w;
            if (d < lo || d >= hi) continue;
            int s = src[e + q];
            if ((unsigned)s >= (unsigned)N) continue;
            int p = atomicAdd(&cursor[d], 1);
            csrc[p] = s;
        }
    }
    if (blockIdx.x == 0) {   // remainder edges: no range filter, handled once here
        for (int e = (E4 << 2) + threadIdx.x; e < E; e += 256) {
            int d = dst[e];
            int s = src[e];
            if ((unsigned)d >= (unsigned)N || (unsigned)s >= (unsigned)N) continue;
            int p = atomicAdd(&cursor[d], 1);
            csrc[p] = s;
        }
    }
}

// ---------- GEMM (layer 1): H[N][128](bf16) = X[N][128](fp32) @ W[128][128](fp32) ----------
__global__ __launch_bounds__(256)
void k_gemm128_a32(const float* __restrict__ X,
                   const float* __restrict__ W,
                   unsigned short* __restrict__ H, int nPairs) {
    int wave = threadIdx.x >> 6;
    int lane = threadIdx.x & 63;
    int ln = lane & 15, quad = lane >> 4;
    int c0 = (wave & 1) * 64;
    int subTile = wave >> 1;

    sh8 bh[4][4], blo[4][4];   // [nt][kt]
    #pragma unroll
    for (int nt = 0; nt < 4; ++nt) {
        int col = c0 + nt * 16 + ln;
        #pragma unroll
        for (int kt = 0; kt < 4; ++kt) {
            int k0 = kt * 32 + quad * 8;
            #pragma unroll
            for (int j = 0; j < 8; ++j) {
                short h, l;
                bfsplit(W[(k0 + j) * 128 + col], h, l);
                bh[nt][kt][j] = h; blo[nt][kt][j] = l;
            }
        }
    }

    for (int p = blockIdx.x; p < nPairs; p += gridDim.x) {
        int nodeBase = p * 32 + subTile * 16;
        const float* xrow = X + (nodeBase + ln) * 128 + quad * 8;
        sh8 ah[4], al[4];
        #pragma unroll
        for (int kt = 0; kt < 4; ++kt) {
            f4 v0 = *(const f4*)(xrow + kt * 32);
            f4 v1 = *(const f4*)(xrow + kt * 32 + 4);
            #pragma unroll
            for (int j = 0; j < 4; ++j) {
                short h, l;
                bfsplit(v0[j], h, l); ah[kt][j] = h; al[kt][j] = l;
                bfsplit(v1[j], h, l); ah[kt][j + 4] = h; al[kt][j + 4] = l;
            }
        }

        f4 acc[4] = { {0.f,0.f,0.f,0.f}, {0.f,0.f,0.f,0.f}, {0.f,0.f,0.f,0.f}, {0.f,0.f,0.f,0.f} };
        #pragma unroll
        for (int kt = 0; kt < 4; ++kt)
            #pragma unroll
            for (int nt = 0; nt < 4; ++nt) {
                acc[nt] = __builtin_amdgcn_mfma_f32_16x16x32_bf16(ah[kt], bh[nt][kt], acc[nt], 0, 0, 0);
                acc[nt] = __builtin_amdgcn_mfma_f32_16x16x32_bf16(ah[kt], blo[nt][kt], acc[nt], 0, 0, 0);
                acc[nt] = __builtin_amdgcn_mfma_f32_16x16x32_bf16(al[kt], bh[nt][kt], acc[nt], 0, 0, 0);
            }

        #pragma unroll
        for (int nt = 0; nt < 4; ++nt) {
            int col = c0 + nt * 16 + ln;
            #pragma unroll
            for (int r = 0; r < 4; ++r)
                H[(nodeBase + quad * 4 + r) * 128 + col] = f2bf(acc[nt][r]);
        }
    }
}

// ---------- GEMM (layers 2,3): H(bf16) = X(bf16) @ W(fp32, split) ----------
__global__ __launch_bounds__(256)
void k_gemm128_a16(const unsigned short* __restrict__ X,
                   const float* __restrict__ W,
                   unsigned short* __restrict__ H, int nPairs) {
    int wave = threadIdx.x >> 6;
    int lane = threadIdx.x & 63;
    int ln = lane & 15, quad = lane >> 4;
    int c0 = (wave & 1) * 64;
    int subTile = wave >> 1;

    sh8 bh[4][4], blo[4][4];
    #pragma unroll
    for (int nt = 0; nt < 4; ++nt) {
        int col = c0 + nt * 16 + ln;
        #pragma unroll
        for (int kt = 0; kt < 4; ++kt) {
            int k0 = kt * 32 + quad * 8;
            #pragma unroll
            for (int j = 0; j < 8; ++j) {
                short h, l;
                bfsplit(W[(k0 + j) * 128 + col], h, l);
                bh[nt][kt][j] = h; blo[nt][kt][j] = l;
            }
        }
    }

    for (int p = blockIdx.x; p < nPairs; p += gridDim.x) {
        int nodeBase = p * 32 + subTile * 16;
        const unsigned short* xrow = X + (nodeBase + ln) * 128 + quad * 8;
        sh8 a[4];
        #pragma unroll
        for (int kt = 0; kt < 4; ++kt) a[kt] = *(const sh8*)(xrow + kt * 32);

        f4 acc[4] = { {0.f,0.f,0.f,0.f}, {0.f,0.f,0.f,0.f}, {0.f,0.f,0.f,0.f}, {0.f,0.f,0.f,0.f} };
        #pragma unroll
        for (int kt = 0; kt < 4; ++kt)
            #pragma unroll
            for (int nt = 0; nt < 4; ++nt) {
                acc[nt] = __builtin_amdgcn_mfma_f32_16x16x32_bf16(a[kt], bh[nt][kt], acc[nt], 0, 0, 0);
                acc[nt] = __builtin_amdgcn_mfma_f32_16x16x32_bf16(a[kt], blo[nt][kt], acc[nt], 0, 0, 0);
            }

        #pragma unroll
        for (int nt = 0; nt < 4; ++nt) {
            int col = c0 + nt * 16 + ln;
            #pragma unroll
            for (int r = 0; r < 4; ++r)
                H[(nodeBase + quad * 4 + r) * 128 + col] = f2bf(acc[nt][r]);
        }
    }
}

// ---------- Aggregation v3: one HALF-WAVE (32 lanes) per node ----------
// Each lane owns 4 bf16 feats (8B); 32 lanes cover the full 256B row. 8 independent
// gathers in flight per node; no cross-lane combine needed.
__global__ __launch_bounds__(256)
void k_agg(const unsigned short* __restrict__ H,
           unsigned short* __restrict__ O,
           const float* __restrict__ dis,
           const int* __restrict__ rowptr,
           const int* __restrict__ cnt,
           const int* __restrict__ csrc,
           const float* __restrict__ bias,
           int relu, int N) {
    int n = (blockIdx.x * 256 + threadIdx.x) >> 5;
    int sub = threadIdx.x & 31;       // feats sub*4 .. sub*4+3
    if (n >= N) return;

    float dn = dis[n];
    float a0, a1, a2, a3;
    {   // self loop
        uint2 v = *(const uint2*)(H + (size_t)n * 128 + sub * 4);
        float w = dn * dn;
        a0 = w * bf2f((unsigned short)v.x);
        a1 = w * bf2f((unsigned short)(v.x >> 16));
        a2 = w * bf2f((unsigned short)v.y);
        a3 = w * bf2f((unsigned short)(v.y >> 16));
    }

    int start = rowptr[n];
    int e = cnt[n];
    int i = 0;
    for (; i + 8 <= e; i += 8) {
        int s[8];
        #pragma unroll
        for (int q = 0; q < 8; ++q) s[q] = csrc[start + i + q];
        uint2 v[8];
        #pragma unroll
        for (int q = 0; q < 8; ++q) v[q] = *(const uint2*)(H + (size_t)s[q] * 128 + sub * 4);
        float w[8];
        #pragma unroll
        for (int q = 0; q < 8; ++q) w[q] = dis[s[q]] * dn;
        #pragma unroll
        for (int q = 0; q < 8; ++q) {
            a0 += w[q] * bf2f((unsigned short)v[q].x);
            a1 += w[q] * bf2f((unsigned short)(v[q].x >> 16));
            a2 += w[q] * bf2f((unsigned short)v[q].y);
            a3 += w[q] * bf2f((unsigned short)(v[q].y >> 16));
        }
    }
    if (i + 4 <= e) {
        int s[4];
        #pragma unroll
        for (int q = 0; q < 4; ++q) s[q] = csrc[start + i + q];
        uint2 v[4];
        #pragma unroll
        for (int q = 0; q < 4; ++q) v[q] = *(const uint2*)(H + (size_t)s[q] * 128 + sub * 4);
        #pragma unroll
        for (int q = 0; q < 4; ++q) {
            float w = dis[s[q]] * dn;
            a0 += w * bf2f((unsigned short)v[q].x);
            a1 += w * bf2f((unsigned short)(v[q].x >> 16));
            a2 += w * bf2f((unsigned short)v[q].y);
            a3 += w * bf2f((unsigned short)(v[q].y >> 16));
        }
        i += 4;
    }
    for (; i < e; ++i) {
        int s0 = csrc[start + i];
        uint2 v = *(const uint2*)(H + (size_t)s0 * 128 + sub * 4);
        float w = dis[s0] * dn;
        a0 += w * bf2f((unsigned short)v.x);
        a1 += w * bf2f((unsigned short)(v.x >> 16));
        a2 += w * bf2f((unsigned short)v.y);
        a3 += w * bf2f((unsigned short)(v.y >> 16));
    }

    f4 b = *(const f4*)(bias + sub * 4);
    a0 += b[0]; a1 += b[1]; a2 += b[2]; a3 += b[3];
    if (relu) {
        a0 = fmaxf(a0, 0.f); a1 = fmaxf(a1, 0.f);
        a2 = fmaxf(a2, 0.f); a3 = fmaxf(a3, 0.f);
    }
    uint2 ov;
    ov.x = (unsigned int)f2bf(a0) | ((unsigned int)f2bf(a1) << 16);
    ov.y = (unsigned int)f2bf(a2) | ((unsigned int)f2bf(a3) << 16);
    *(uint2*)(O + (size_t)n * 128 + sub * 4) = ov;
}

// ---------- Final head: OUT[N][40](fp32) = X(bf16) @ Wl(fp32 split) + bl ----------
__global__ __launch_bounds__(256)
void k_gemm_final(const unsigned short* __restrict__ X,
                  const float* __restrict__ W,     // [128][40]
                  const float* __restrict__ bl,    // [40]
                  float* __restrict__ OUT, int nTiles) {
    int wave = threadIdx.x >> 6;
    int lane = threadIdx.x & 63;
    int ln = lane & 15, quad = lane >> 4;
    int tile = blockIdx.x * 4 + wave;
    if (tile >= nTiles) return;

    sh8 bh[3][4], blo[3][4];
    #pragma unroll
    for (int nt = 0; nt < 3; ++nt) {
        int col = nt * 16 + ln;
        bool valid = (col < 40);
        #pragma unroll
        for (int kt = 0; kt < 4; ++kt) {
            int k0 = kt * 32 + quad * 8;
            #pragma unroll
            for (int j = 0; j < 8; ++j) {
                short h = 0, l = 0;
                if (valid) bfsplit(W[(k0 + j) * 40 + col], h, l);
                bh[nt][kt][j] = h; blo[nt][kt][j] = l;
            }
        }
    }

    int nodeBase = tile * 16;
    const unsigned short* xrow = X + (nodeBase + ln) * 128 + quad * 8;
    sh8 a[4];
    #pragma unroll
    for (int kt = 0; kt < 4; ++kt) a[kt] = *(const sh8*)(xrow + kt * 32);

    f4 acc[3] = { {0.f,0.f,0.f,0.f}, {0.f,0.f,0.f,0.f}, {0.f,0.f,0.f,0.f} };
    #pragma unroll
    for (int kt = 0; kt < 4; ++kt)
        #pragma unroll
        for (int nt = 0; nt < 3; ++nt) {
            acc[nt] = __builtin_amdgcn_mfma_f32_16x16x32_bf16(a[kt], bh[nt][kt], acc[nt], 0, 0, 0);
            acc[nt] = __builtin_amdgcn_mfma_f32_16x16x32_bf16(a[kt], blo[nt][kt], acc[nt], 0, 0, 0);
        }

    #pragma unroll
    for (int nt = 0; nt < 3; ++nt) {
        int col = nt * 16 + ln;
        if (col < 40) {
            float bv = bl[col];
            #pragma unroll
            for (int r = 0; r < 4; ++r)
                OUT[(nodeBase + quad * 4 + r) * 40 + col] = acc[nt][r] + bv;
        }
    }
}

// ---------- launch ----------
extern "C" void kernel_launch(void* const* d_in, const int* in_sizes, int n_in,
                              void* d_out, int out_size, void* d_ws, size_t ws_size,
                              hipStream_t stream) {
    const float* x  = (const float*)d_in[0];
    const int*   ei = (const int*)d_in[1];
    const float* W1 = (const float*)d_in[2];
    const float* b1 = (const float*)d_in[3];
    const float* W2 = (const float*)d_in[4];
    const float* b2 = (const float*)d_in[5];
    const float* W3 = (const float*)d_in[6];
    const float* b3 = (const float*)d_in[7];
    const float* Wl = (const float*)d_in[8];
    const float* bl = (const float*)d_in[9];

    const int N = in_sizes[0] / 128;   // 100000
    const int E = in_sizes[1] / 2;     // 1600000
    const int* srcIdx = ei;
    const int* dstIdx = ei + E;

    char* ws = (char*)d_ws;
    size_t off = 0;
    auto alloc = [&](size_t bytes) { void* p = ws + off; off += (bytes + 511) & ~(size_t)511; return p; };
    int*   cnt     = (int*)  alloc((size_t)N * 4);
    int*   rowptr  = (int*)  alloc((size_t)N * 4);
    int*   cursor  = (int*)  alloc((size_t)N * 4);
    float* dis     = (float*)alloc((size_t)N * 4);
    int*   bsum    = (int*)  alloc(512 * 4);
    int*   csrc    = (int*)  alloc((size_t)E * 4);
    unsigned short* h0 = (unsigned short*)alloc((size_t)N * 128 * 2);
    unsigned short* h1 = (unsigned short*)alloc((size_t)N * 128 * 2);

    const int gN = (N + 255) / 256;           // 391
    const int nPairs = N / 32;                // 3125
    const int nTiles = N / 16;                // 6250
    const int gAgg = (N * 32 + 255) / 256;    // 12500 (half-wave per node)
    const int gPart = 1024;                   // 8 dst-range groups x 128 blocks (fill)

    // CSR build
    k_zero_cnt<<<gN, 256, 0, stream>>>(cnt, N);
    k_count<<<768, 256, 0, stream>>>(dstIdx, cnt, E, N);
    k_scan_a<<<gN, 256, 0, stream>>>(cnt, rowptr, bsum, dis, N);
    k_scan_b<<<1, 512, 0, stream>>>(bsum, gN);
    k_scan_c<<<gN, 256, 0, stream>>>(rowptr, cursor, bsum, N);
    k_fill<<<gPart, 256, 0, stream>>>(srcIdx, dstIdx, cursor, csrc, E, N);

    // Layer 1
    k_gemm128_a32<<<768, 256, 0, stream>>>(x, W1, h0, nPairs);
    k_agg<<<gAgg, 256, 0, stream>>>(h0, h1, dis, rowptr, cnt, csrc, b1, 1, N);
    // Layer 2
    k_gemm128_a16<<<768, 256, 0, stream>>>(h1, W2, h0, nPairs);
    k_agg<<<gAgg, 256, 0, stream>>>(h0, h1, dis, rowptr, cnt, csrc, b2, 1, N);
    // Layer 3 (no relu)
    k_gemm128_a16<<<768, 256, 0, stream>>>(h1, W3, h0, nPairs);
    k_agg<<<gAgg, 256, 0, stream>>>(h0, h1, dis, rowptr, cnt, csrc, b3, 0, N);
    // Head
    k_gemm_final<<<(nTiles + 3) / 4, 256, 0, stream>>>(h1, Wl, bl, (float*)d_out, nTiles);
}